// Round 5
// baseline (199.579 us; speedup 1.0000x reference)
//
#include <hip/hip_runtime.h>
#include <math.h>

// MultiHeadAttention: B=2, S=2048, D=1024, H=16, Dh=64, fp32 in/out.
// Round 5: bf16-MFMA pipeline.
//  - GEMM: LDS-staged coalesced epilogue (uint4 stores for Q/K/V^T),
//          Q pre-scaled by 0.125*log2(e) (softmax runs in exp2 domain).
//  - attn: pair-balanced blocks (qt=31-p then qt=p -> uniform 33 iters),
//          exp2 softmax, defer-max rescale skip (T13).
// Workspace: qb,kb,vtb,xb (4 x 8.39 MB bf16) + wt (8.39 MB) = 41.9 MB.

#define H_  16
#define DH_ 64
#define D_  1024
#define S_  2048
#define B_  2

typedef __attribute__((ext_vector_type(8))) short short8;
typedef __attribute__((ext_vector_type(4))) float f32x4;

#define QSCALE 0.18033688011112042f      // log2(e)/8, folded into Q
#define DEFER_THR 11.5416f               // 8*log2(e): defer-max threshold

__device__ __forceinline__ unsigned short f2bf(float f) {
    union { float f; unsigned int u; } v; v.f = f;
    unsigned int r = (v.u + 0x7fffu + ((v.u >> 16) & 1u)) >> 16;   // RNE
    return (unsigned short)r;
}

__device__ __forceinline__ float fast_exp2(float x) {
#if __has_builtin(__builtin_amdgcn_exp2f)
    return __builtin_amdgcn_exp2f(x);
#else
    return exp2f(x);
#endif
}

__device__ __forceinline__ void gload_lds16(const void* g, void* l) {
    __builtin_amdgcn_global_load_lds(
        (const __attribute__((address_space(1))) void*)g,
        (__attribute__((address_space(3))) void*)l, 16, 0, 0);
}

// ---------------------------------------------------------------------------
// x fp32 [4096][1024] -> bf16. 8 elems/thread.
// ---------------------------------------------------------------------------
__global__ __launch_bounds__(256) void cvt_x_k(const float* __restrict__ x,
                                               unsigned short* __restrict__ xb)
{
    int i = (blockIdx.x * 256 + threadIdx.x) * 8;
    float4 a = *(const float4*)&x[i];
    float4 b = *(const float4*)&x[i + 4];
    uint4 o;
    o.x = f2bf(a.x) | ((unsigned)f2bf(a.y) << 16);
    o.y = f2bf(a.z) | ((unsigned)f2bf(a.w) << 16);
    o.z = f2bf(b.x) | ((unsigned)f2bf(b.y) << 16);
    o.w = f2bf(b.z) | ((unsigned)f2bf(b.w) << 16);
    *(uint4*)&xb[i] = o;
}

// ---------------------------------------------------------------------------
// W fp32 [k][n] -> Wt bf16 [n][k]. 64x64 LDS-tiled transpose. z: Wq/Wk/Wv/Wo.
// ---------------------------------------------------------------------------
__global__ __launch_bounds__(256) void tr_w_k(
    const float* __restrict__ W0, const float* __restrict__ W1,
    const float* __restrict__ W2, const float* __restrict__ W3,
    unsigned short* __restrict__ wt)
{
    const float* W = W0;
    if (blockIdx.z == 1) W = W1; else if (blockIdx.z == 2) W = W2;
    else if (blockIdx.z == 3) W = W3;
    unsigned short* out = wt + (size_t)blockIdx.z * 1048576;

    __shared__ float t[64][65];
    const int k0 = blockIdx.x * 64, n0 = blockIdx.y * 64;
    const int r = threadIdx.x >> 4, c4 = (threadIdx.x & 15) * 4;

    #pragma unroll
    for (int p = 0; p < 4; ++p) {
        float4 v = *(const float4*)&W[(size_t)(k0 + r + 16 * p) * D_ + n0 + c4];
        t[r + 16 * p][c4 + 0] = v.x; t[r + 16 * p][c4 + 1] = v.y;
        t[r + 16 * p][c4 + 2] = v.z; t[r + 16 * p][c4 + 3] = v.w;
    }
    __syncthreads();
    #pragma unroll
    for (int p = 0; p < 4; ++p) {
        int nn = r + 16 * p;
        uint2 o;
        o.x = f2bf(t[c4 + 0][nn]) | ((unsigned)f2bf(t[c4 + 1][nn]) << 16);
        o.y = f2bf(t[c4 + 2][nn]) | ((unsigned)f2bf(t[c4 + 3][nn]) << 16);
        *(uint2*)&out[(size_t)(n0 + nn) * D_ + k0 + c4] = o;
    }
}

// ---------------------------------------------------------------------------
// bf16 MFMA GEMM, 128x128 tile, BK=64, 4 waves (2x2), 4x4 frags.
// LDS XOR-slot swizzle, global_load_lds staging.
// QKV=1: z selects q/k/v; Q (pre-scaled by QSCALE), K -> bf16 [B,H,S,64];
//        V -> bf16 [B,H,64,S]. All via LDS-staged coalesced uint4 stores.
// QKV=0: fp32 row-major + bias.
// ---------------------------------------------------------------------------
template<int QKV>
__global__ __launch_bounds__(256) void gemm_bf16(
    const unsigned short* __restrict__ Ab,
    const unsigned short* __restrict__ Wt,
    const float* __restrict__ b0, const float* __restrict__ b1,
    const float* __restrict__ b2,
    void* __restrict__ o0, void* __restrict__ o1, void* __restrict__ o2)
{
    const unsigned short* W = Wt;
    const float* bias = b0;
    int z = 0;
    if (QKV) {
        z = blockIdx.z;
        W = Wt + (size_t)z * 1048576;
        if (z == 1) bias = b1; else if (z == 2) bias = b2;
    }
    const int n0 = blockIdx.x * 128, j0 = blockIdx.y * 128;
    const int tid = threadIdx.x;
    const int lane = tid & 63;
    const int wq = tid >> 6, wm = wq >> 1, wn = wq & 1;
    const int lr = lane & 15, lk = lane >> 4;

    __shared__ __align__(16) char smem[32768];

    f32x4 acc[4][4] = {};

    for (int k0 = 0; k0 < D_; k0 += 64) {
        __syncthreads();
        #pragma unroll
        for (int c = 0; c < 4; ++c) {
            int u = c * 256 + tid;
            int r = u >> 3, sp = u & 7, sl = sp ^ (r & 7);
            gload_lds16(&Ab[(size_t)(n0 + r) * D_ + k0 + sl * 8], &smem[u * 16]);
        }
        #pragma unroll
        for (int c = 0; c < 4; ++c) {
            int u = c * 256 + tid;
            int r = u >> 3, sp = u & 7, sl = sp ^ (r & 7);
            gload_lds16(&W[(size_t)(j0 + r) * D_ + k0 + sl * 8],
                        &smem[16384 + u * 16]);
        }
        __syncthreads();
        #pragma unroll
        for (int kc = 0; kc < 2; ++kc) {
            short8 a[4], b[4];
            #pragma unroll
            for (int m = 0; m < 4; ++m) {
                int row = wm * 64 + m * 16 + lr;
                int sp = (kc * 4 + lk) ^ (row & 7);
                a[m] = *(const short8*)&smem[row * 128 + sp * 16];
            }
            #pragma unroll
            for (int n = 0; n < 4; ++n) {
                int row = wn * 64 + n * 16 + lr;
                int sp = (kc * 4 + lk) ^ (row & 7);
                b[n] = *(const short8*)&smem[16384 + row * 128 + sp * 16];
            }
            #pragma unroll
            for (int m = 0; m < 4; ++m)
                #pragma unroll
                for (int n = 0; n < 4; ++n)
                    acc[m][n] = __builtin_amdgcn_mfma_f32_16x16x32_bf16(
                        a[m], b[n], acc[m][n], 0, 0, 0);
        }
    }

    float bn[4];
    #pragma unroll
    for (int n = 0; n < 4; ++n) bn[n] = bias[j0 + wn * 64 + n * 16 + lr];

    if (QKV) {
        // ---- LDS-staged coalesced epilogue ----
        __syncthreads();                      // all waves done reading tiles
        char* ep = smem + wq * 8192;          // 64 rows x 128 B, XOR-swizzled
        const int head = (j0 + wn * 64) >> 6;
        const int row0 = n0 + wm * 64;
        const float sc = (z == 0) ? QSCALE : 1.0f;

        if (z < 2) {
            // tile[s][dh]: row = m*16+lk*4+r (s), col = n*16+lr (dh)
            #pragma unroll
            for (int m = 0; m < 4; ++m)
                #pragma unroll
                for (int n = 0; n < 4; ++n) {
                    int col = n * 16 + lr;
                    #pragma unroll
                    for (int r = 0; r < 4; ++r) {
                        int row = m * 16 + lk * 4 + r;
                        int phys = (col >> 3) ^ (row & 7);
                        *(unsigned short*)&ep[row * 128 + phys * 16 + (col & 7) * 2]
                            = f2bf((acc[m][n][r] + bn[n]) * sc);
                    }
                }
            unsigned short* out = (unsigned short*)(z == 0 ? o0 : o1);
            #pragma unroll
            for (int p8 = 0; p8 < 8; ++p8) {
                int row = p8 * 8 + (lane >> 3);
                int phys = (lane & 7) ^ (row & 7);
                uint4 pk = *(const uint4*)&ep[row * 128 + phys * 16];
                int nrow = row0 + row;
                int bb = nrow >> 11, s = nrow & (S_ - 1);
                *(uint4*)&out[(((size_t)(bb * H_ + head)) * S_ + s) * 64
                              + (lane & 7) * 8] = pk;
            }
        } else {
            // V^T tile[dh][s]: row = n*16+lr (dh), col = m*16+lk*4+r (s)
            #pragma unroll
            for (int m = 0; m < 4; ++m)
                #pragma unroll
                for (int n = 0; n < 4; ++n) {
                    int row = n * 16 + lr;
                    #pragma unroll
                    for (int r = 0; r < 4; ++r) {
                        int col = m * 16 + lk * 4 + r;
                        int phys = (col >> 3) ^ (row & 7);
                        *(unsigned short*)&ep[row * 128 + phys * 16 + (col & 7) * 2]
                            = f2bf(acc[m][n][r] + bn[n]);
                    }
                }
            unsigned short* out = (unsigned short*)o2;
            int bb = row0 >> 11, s0 = row0 & (S_ - 1);
            #pragma unroll
            for (int p8 = 0; p8 < 8; ++p8) {
                int dh = p8 * 8 + (lane >> 3);
                int phys = (lane & 7) ^ (dh & 7);
                uint4 pk = *(const uint4*)&ep[dh * 128 + phys * 16];
                *(uint4*)&out[(((size_t)(bb * H_ + head)) * 64 + dh) * S_
                              + s0 + (lane & 7) * 8] = pk;
            }
        }
    } else {
        float* out = (float*)o0;
        #pragma unroll
        for (int m = 0; m < 4; ++m)
            #pragma unroll
            for (int n = 0; n < 4; ++n) {
                int col = j0 + wn * 64 + n * 16 + lr;
                int row0 = n0 + wm * 64 + m * 16 + lk * 4;
                #pragma unroll
                for (int r = 0; r < 4; ++r)
                    out[(size_t)(row0 + r) * D_ + col] = acc[m][n][r] + bn[n];
            }
    }
}

// ---------------------------------------------------------------------------
// MFMA flash attention. grid = (B*H, 16 pairs), 256 thr = 4 waves x 16 q-rows.
// Each block handles qt = 31-p then qt = p  -> uniform 33 kv-iters/block.
// Swapped QK^T -> scores lane-local; softmax in exp2 domain (Q pre-scaled by
// log2(e)/8); defer-max skips O-rescale when max grows < 8 (ln) per tile.
// ---------------------------------------------------------------------------
__global__ __launch_bounds__(256) void attn_mfma(
    const unsigned short* __restrict__ q, const unsigned short* __restrict__ k,
    const unsigned short* __restrict__ vt, unsigned short* __restrict__ ctx)
{
    const int bh = blockIdx.x;          // b*H + h
    const int tid = threadIdx.x;
    const int lane = tid & 63, wq = tid >> 6;
    const int lx = lane & 15, hi = lane >> 4;

    // [0,8K) K tile  [8K,16K) V^T tile  [16K,24K) P tiles (2KB/wave)
    __shared__ __align__(16) char smem[24576];
    char* Pw = &smem[16384 + wq * 2048];

    const int b = bh >> 4, h = bh & (H_ - 1);

    for (int half = 0; half < 2; ++half) {
        const int qt = half ? blockIdx.y : 31 - blockIdx.y;

        short8 qf[2];
        {
            const unsigned short* qrow =
                q + ((size_t)bh * S_ + qt * 64 + wq * 16 + lx) * 64;
            qf[0] = *(const short8*)&qrow[hi * 8];
            qf[1] = *(const short8*)&qrow[32 + hi * 8];
        }

        f32x4 o[4] = {};                    // O[hi*4+r][ct*16+lx]
        float m = -INFINITY, l = 0.f;       // state for q-row (wq*16+lx)
        const int qg = qt * 64 + wq * 16 + lx;

        for (int kt = 0; kt <= qt; ++kt) {
            __syncthreads();                // prev iter's K/V reads done
            #pragma unroll
            for (int c = 0; c < 2; ++c) {   // K tile: 64 rows x 128 B
                int u = c * 256 + tid;
                int r = u >> 3, sp = u & 7, sl = sp ^ (r & 7);
                gload_lds16(&k[((size_t)bh * S_ + kt * 64 + r) * 64 + sl * 8],
                            &smem[u * 16]);
            }
            #pragma unroll
            for (int c = 0; c < 2; ++c) {   // V^T tile: 64 d-rows x 128 B
                int u = c * 256 + tid;
                int r = u >> 3, sp = u & 7, sl = sp ^ (r & 7);
                gload_lds16(&vt[((size_t)bh * 64 + r) * S_ + kt * 64 + sl * 8],
                            &smem[8192 + u * 16]);
            }
            __syncthreads();

            // ---- QK^T (swapped): lane holds S[q=lx][kv=rt*16+hi*4+r] ----
            f32x4 s[4] = {};
            #pragma unroll
            for (int rt = 0; rt < 4; ++rt) {
                #pragma unroll
                for (int ks = 0; ks < 2; ++ks) {
                    int row = rt * 16 + lx;
                    int sp = (ks * 4 + hi) ^ (row & 7);
                    short8 kf = *(const short8*)&smem[row * 128 + sp * 16];
                    s[rt] = __builtin_amdgcn_mfma_f32_16x16x32_bf16(
                        kf, qf[ks], s[rt], 0, 0, 0);
                }
            }

            // ---- causal mask (scale already folded into Q) ----
            if (kt == qt) {
                #pragma unroll
                for (int rt = 0; rt < 4; ++rt)
                    #pragma unroll
                    for (int r = 0; r < 4; ++r) {
                        int kvg = kt * 64 + rt * 16 + hi * 4 + r;
                        if (kvg > qg) s[rt][r] = -INFINITY;
                    }
            }

            // ---- online softmax in exp2 domain, row = lx ----
            float tmax = s[0][0];
            #pragma unroll
            for (int rt = 0; rt < 4; ++rt)
                tmax = fmaxf(tmax, fmaxf(fmaxf(s[rt][0], s[rt][1]),
                                         fmaxf(s[rt][2], s[rt][3])));
            tmax = fmaxf(tmax, __shfl_xor(tmax, 16));
            tmax = fmaxf(tmax, __shfl_xor(tmax, 32));

            if (__any(tmax > m + DEFER_THR)) {
                float mn = fmaxf(m, tmax);
                float corr = fast_exp2(m - mn);
                m = mn;
                float ps = 0.f;
                #pragma unroll
                for (int rt = 0; rt < 4; ++rt)
                    #pragma unroll
                    for (int r = 0; r < 4; ++r) {
                        s[rt][r] = fast_exp2(s[rt][r] - mn);
                        ps += s[rt][r];
                    }
                ps += __shfl_xor(ps, 16);
                ps += __shfl_xor(ps, 32);
                l = l * corr + ps;
                #pragma unroll
                for (int r = 0; r < 4; ++r) {
                    float cr = __shfl(corr, hi * 4 + r);
                    #pragma unroll
                    for (int ct = 0; ct < 4; ++ct) o[ct][r] *= cr;
                }
            } else {                        // deferred: m unchanged, corr = 1
                float ps = 0.f;
                #pragma unroll
                for (int rt = 0; rt < 4; ++rt)
                    #pragma unroll
                    for (int r = 0; r < 4; ++r) {
                        s[rt][r] = fast_exp2(s[rt][r] - m);
                        ps += s[rt][r];
                    }
                ps += __shfl_xor(ps, 16);
                ps += __shfl_xor(ps, 32);
                l += ps;
            }

            // ---- P -> bf16 -> per-wave swizzled LDS tile [16 q][64 kv] ----
            #pragma unroll
            for (int rt = 0; rt < 4; ++rt) {
                uint2 pk;
                pk.x = f2bf(s[rt][0]) | ((unsigned)f2bf(s[rt][1]) << 16);
                pk.y = f2bf(s[rt][2]) | ((unsigned)f2bf(s[rt][3]) << 16);
                int sl = 2 * rt + (hi >> 1);
                *(uint2*)&Pw[lx * 128 + ((sl ^ (lx & 7)) * 16) + (hi & 1) * 8] = pk;
            }
            short8 pf[2];
            #pragma unroll
            for (int ks = 0; ks < 2; ++ks) {
                int sl = ks * 4 + hi;
                pf[ks] = *(const short8*)&Pw[lx * 128 + ((sl ^ (lx & 7)) * 16)];
            }

            // ---- PV: O[q][d] += P . V^T ----
            #pragma unroll
            for (int ct = 0; ct < 4; ++ct) {
                #pragma unroll
                for (int ks = 0; ks < 2; ++ks) {
                    int row = ct * 16 + lx;
                    int sp = (ks * 4 + hi) ^ (row & 7);
                    short8 vf = *(const short8*)&smem[8192 + row * 128 + sp * 16];
                    o[ct] = __builtin_amdgcn_mfma_f32_16x16x32_bf16(
                        pf[ks], vf, o[ct], 0, 0, 0);
                }
            }
        }

        // ---- epilogue: ctx bf16 [B,S,D] ----
        #pragma unroll
        for (int r = 0; r < 4; ++r) {
            float inv = 1.0f / __shfl(l, hi * 4 + r);
            int srow = qt * 64 + wq * 16 + hi * 4 + r;
            #pragma unroll
            for (int ct = 0; ct < 4; ++ct)
                ctx[((size_t)(b * S_ + srow)) * D_ + h * 64 + ct * 16 + lx] =
                    f2bf(o[ct][r] * inv);
        }
        __syncthreads();                    // smem reuse across halves
    }
}

// ---------------------------------------------------------------------------
extern "C" void kernel_launch(void* const* d_in, const int* in_sizes, int n_in,
                              void* d_out, int out_size, void* d_ws, size_t ws_size,
                              hipStream_t stream)
{
    const float* x  = (const float*)d_in[0];
    const float* Wq = (const float*)d_in[1];
    const float* bq = (const float*)d_in[2];
    const float* Wk = (const float*)d_in[3];
    const float* bk = (const float*)d_in[4];
    const float* Wv = (const float*)d_in[5];
    const float* bv = (const float*)d_in[6];
    const float* Wo = (const float*)d_in[7];
    const float* bo = (const float*)d_in[8];
    float* out = (float*)d_out;

    const size_t per = (size_t)B_ * H_ * S_ * DH_;       // 4,194,304
    unsigned short* qb  = (unsigned short*)d_ws;
    unsigned short* kb  = qb + per;
    unsigned short* vtb = kb + per;
    unsigned short* xb  = vtb + per;
    unsigned short* wt  = xb + per;                      // 4 x 1M bf16
    unsigned short* cb  = xb;                            // ctx aliases xb

    cvt_x_k<<<2048, 256, 0, stream>>>(x, xb);
    tr_w_k<<<dim3(16, 16, 4), 256, 0, stream>>>(Wq, Wk, Wv, Wo, wt);

    gemm_bf16<1><<<dim3(32, 8, 3), 256, 0, stream>>>(
        xb, wt, bq, bk, bv, qb, kb, vtb);

    attn_mfma<<<dim3(32, 16), 256, 0, stream>>>(qb, kb, vtb, cb);

    gemm_bf16<0><<<dim3(32, 8, 1), 256, 0, stream>>>(
        cb, wt + 3u * 1048576u, bo, nullptr, nullptr, out, nullptr, nullptr);
}

// Round 6
// 197.479 us; speedup vs baseline: 1.0106x; 1.0106x over previous
//
#include <hip/hip_runtime.h>
#include <math.h>

// MultiHeadAttention: B=2, S=2048, D=1024, H=16, Dh=64, fp32 in/out.
// Round 6: attn restructured for latency hiding.
//  - K/V double-buffered in LDS (2x16KB), ONE raw s_barrier per kv-iter with
//    vmcnt(0) drain AFTER compute -> next tile's loads hide under compute.
//  - P-pack via v_cvt_pk_bf16_f32 inline asm (80 -> 8 VALU/iter).
//  - grid (32,32) heavy-first, 4 blocks/CU (40KB LDS each = 160KB exactly).
// GEMMs unchanged from round 5.

#define H_  16
#define DH_ 64
#define D_  1024
#define S_  2048
#define B_  2

typedef __attribute__((ext_vector_type(8))) short short8;
typedef __attribute__((ext_vector_type(4))) float f32x4;

#define QSCALE 0.18033688011112042f      // log2(e)/8, folded into Q
#define DEFER_THR 11.5416f               // 8*log2(e): defer-max threshold

__device__ __forceinline__ unsigned short f2bf(float f) {
    union { float f; unsigned int u; } v; v.f = f;
    unsigned int r = (v.u + 0x7fffu + ((v.u >> 16) & 1u)) >> 16;   // RNE
    return (unsigned short)r;
}

__device__ __forceinline__ unsigned cvt_pk_bf16(float lo, float hi) {
    unsigned r;
    asm("v_cvt_pk_bf16_f32 %0, %1, %2" : "=v"(r) : "v"(lo), "v"(hi));
    return r;
}

__device__ __forceinline__ float fast_exp2(float x) {
#if __has_builtin(__builtin_amdgcn_exp2f)
    return __builtin_amdgcn_exp2f(x);
#else
    return exp2f(x);
#endif
}

__device__ __forceinline__ void gload_lds16(const void* g, void* l) {
    __builtin_amdgcn_global_load_lds(
        (const __attribute__((address_space(1))) void*)g,
        (__attribute__((address_space(3))) void*)l, 16, 0, 0);
}

// vmcnt(0) drain + workgroup barrier, WITHOUT lgkm drain (P-tile is per-wave).
#define SYNC_VM0() asm volatile("s_waitcnt vmcnt(0)\n\ts_barrier" ::: "memory")

// ---------------------------------------------------------------------------
// x fp32 [4096][1024] -> bf16. 8 elems/thread.
// ---------------------------------------------------------------------------
__global__ __launch_bounds__(256) void cvt_x_k(const float* __restrict__ x,
                                               unsigned short* __restrict__ xb)
{
    int i = (blockIdx.x * 256 + threadIdx.x) * 8;
    float4 a = *(const float4*)&x[i];
    float4 b = *(const float4*)&x[i + 4];
    uint4 o;
    o.x = f2bf(a.x) | ((unsigned)f2bf(a.y) << 16);
    o.y = f2bf(a.z) | ((unsigned)f2bf(a.w) << 16);
    o.z = f2bf(b.x) | ((unsigned)f2bf(b.y) << 16);
    o.w = f2bf(b.z) | ((unsigned)f2bf(b.w) << 16);
    *(uint4*)&xb[i] = o;
}

// ---------------------------------------------------------------------------
// W fp32 [k][n] -> Wt bf16 [n][k]. 64x64 LDS-tiled transpose. z: Wq/Wk/Wv/Wo.
// ---------------------------------------------------------------------------
__global__ __launch_bounds__(256) void tr_w_k(
    const float* __restrict__ W0, const float* __restrict__ W1,
    const float* __restrict__ W2, const float* __restrict__ W3,
    unsigned short* __restrict__ wt)
{
    const float* W = W0;
    if (blockIdx.z == 1) W = W1; else if (blockIdx.z == 2) W = W2;
    else if (blockIdx.z == 3) W = W3;
    unsigned short* out = wt + (size_t)blockIdx.z * 1048576;

    __shared__ float t[64][65];
    const int k0 = blockIdx.x * 64, n0 = blockIdx.y * 64;
    const int r = threadIdx.x >> 4, c4 = (threadIdx.x & 15) * 4;

    #pragma unroll
    for (int p = 0; p < 4; ++p) {
        float4 v = *(const float4*)&W[(size_t)(k0 + r + 16 * p) * D_ + n0 + c4];
        t[r + 16 * p][c4 + 0] = v.x; t[r + 16 * p][c4 + 1] = v.y;
        t[r + 16 * p][c4 + 2] = v.z; t[r + 16 * p][c4 + 3] = v.w;
    }
    __syncthreads();
    #pragma unroll
    for (int p = 0; p < 4; ++p) {
        int nn = r + 16 * p;
        uint2 o;
        o.x = f2bf(t[c4 + 0][nn]) | ((unsigned)f2bf(t[c4 + 1][nn]) << 16);
        o.y = f2bf(t[c4 + 2][nn]) | ((unsigned)f2bf(t[c4 + 3][nn]) << 16);
        *(uint2*)&out[(size_t)(n0 + nn) * D_ + k0 + c4] = o;
    }
}

// ---------------------------------------------------------------------------
// bf16 MFMA GEMM, 128x128 tile, BK=64, 4 waves (2x2), 4x4 frags.
// LDS XOR-slot swizzle, global_load_lds staging, LDS-staged coalesced epilogue.
// QKV=1: z selects q/k/v; Q (pre-scaled), K -> bf16 [B,H,S,64]; V -> [B,H,64,S].
// QKV=0: fp32 row-major + bias.
// ---------------------------------------------------------------------------
template<int QKV>
__global__ __launch_bounds__(256) void gemm_bf16(
    const unsigned short* __restrict__ Ab,
    const unsigned short* __restrict__ Wt,
    const float* __restrict__ b0, const float* __restrict__ b1,
    const float* __restrict__ b2,
    void* __restrict__ o0, void* __restrict__ o1, void* __restrict__ o2)
{
    const unsigned short* W = Wt;
    const float* bias = b0;
    int z = 0;
    if (QKV) {
        z = blockIdx.z;
        W = Wt + (size_t)z * 1048576;
        if (z == 1) bias = b1; else if (z == 2) bias = b2;
    }
    const int n0 = blockIdx.x * 128, j0 = blockIdx.y * 128;
    const int tid = threadIdx.x;
    const int lane = tid & 63;
    const int wq = tid >> 6, wm = wq >> 1, wn = wq & 1;
    const int lr = lane & 15, lk = lane >> 4;

    __shared__ __align__(16) char smem[32768];

    f32x4 acc[4][4] = {};

    for (int k0 = 0; k0 < D_; k0 += 64) {
        __syncthreads();
        #pragma unroll
        for (int c = 0; c < 4; ++c) {
            int u = c * 256 + tid;
            int r = u >> 3, sp = u & 7, sl = sp ^ (r & 7);
            gload_lds16(&Ab[(size_t)(n0 + r) * D_ + k0 + sl * 8], &smem[u * 16]);
        }
        #pragma unroll
        for (int c = 0; c < 4; ++c) {
            int u = c * 256 + tid;
            int r = u >> 3, sp = u & 7, sl = sp ^ (r & 7);
            gload_lds16(&W[(size_t)(j0 + r) * D_ + k0 + sl * 8],
                        &smem[16384 + u * 16]);
        }
        __syncthreads();
        #pragma unroll
        for (int kc = 0; kc < 2; ++kc) {
            short8 a[4], b[4];
            #pragma unroll
            for (int m = 0; m < 4; ++m) {
                int row = wm * 64 + m * 16 + lr;
                int sp = (kc * 4 + lk) ^ (row & 7);
                a[m] = *(const short8*)&smem[row * 128 + sp * 16];
            }
            #pragma unroll
            for (int n = 0; n < 4; ++n) {
                int row = wn * 64 + n * 16 + lr;
                int sp = (kc * 4 + lk) ^ (row & 7);
                b[n] = *(const short8*)&smem[16384 + row * 128 + sp * 16];
            }
            #pragma unroll
            for (int m = 0; m < 4; ++m)
                #pragma unroll
                for (int n = 0; n < 4; ++n)
                    acc[m][n] = __builtin_amdgcn_mfma_f32_16x16x32_bf16(
                        a[m], b[n], acc[m][n], 0, 0, 0);
        }
    }

    float bn[4];
    #pragma unroll
    for (int n = 0; n < 4; ++n) bn[n] = bias[j0 + wn * 64 + n * 16 + lr];

    if (QKV) {
        __syncthreads();
        char* ep = smem + wq * 8192;          // 64 rows x 128 B, XOR-swizzled
        const int head = (j0 + wn * 64) >> 6;
        const int row0 = n0 + wm * 64;
        const float sc = (z == 0) ? QSCALE : 1.0f;

        if (z < 2) {
            #pragma unroll
            for (int m = 0; m < 4; ++m)
                #pragma unroll
                for (int n = 0; n < 4; ++n) {
                    int col = n * 16 + lr;
                    #pragma unroll
                    for (int r = 0; r < 4; ++r) {
                        int row = m * 16 + lk * 4 + r;
                        int phys = (col >> 3) ^ (row & 7);
                        *(unsigned short*)&ep[row * 128 + phys * 16 + (col & 7) * 2]
                            = f2bf((acc[m][n][r] + bn[n]) * sc);
                    }
                }
            unsigned short* out = (unsigned short*)(z == 0 ? o0 : o1);
            #pragma unroll
            for (int p8 = 0; p8 < 8; ++p8) {
                int row = p8 * 8 + (lane >> 3);
                int phys = (lane & 7) ^ (row & 7);
                uint4 pk = *(const uint4*)&ep[row * 128 + phys * 16];
                int nrow = row0 + row;
                int bb = nrow >> 11, s = nrow & (S_ - 1);
                *(uint4*)&out[(((size_t)(bb * H_ + head)) * S_ + s) * 64
                              + (lane & 7) * 8] = pk;
            }
        } else {
            #pragma unroll
            for (int m = 0; m < 4; ++m)
                #pragma unroll
                for (int n = 0; n < 4; ++n) {
                    int row = n * 16 + lr;
                    #pragma unroll
                    for (int r = 0; r < 4; ++r) {
                        int col = m * 16 + lk * 4 + r;
                        int phys = (col >> 3) ^ (row & 7);
                        *(unsigned short*)&ep[row * 128 + phys * 16 + (col & 7) * 2]
                            = f2bf(acc[m][n][r] + bn[n]);
                    }
                }
            unsigned short* out = (unsigned short*)o2;
            int bb = row0 >> 11, s0 = row0 & (S_ - 1);
            #pragma unroll
            for (int p8 = 0; p8 < 8; ++p8) {
                int dh = p8 * 8 + (lane >> 3);
                int phys = (lane & 7) ^ (dh & 7);
                uint4 pk = *(const uint4*)&ep[dh * 128 + phys * 16];
                *(uint4*)&out[(((size_t)(bb * H_ + head)) * 64 + dh) * S_
                              + s0 + (lane & 7) * 8] = pk;
            }
        }
    } else {
        float* out = (float*)o0;
        #pragma unroll
        for (int m = 0; m < 4; ++m)
            #pragma unroll
            for (int n = 0; n < 4; ++n) {
                int col = j0 + wn * 64 + n * 16 + lr;
                int row0 = n0 + wm * 64 + m * 16 + lk * 4;
                #pragma unroll
                for (int r = 0; r < 4; ++r)
                    out[(size_t)(row0 + r) * D_ + col] = acc[m][n][r] + bn[n];
            }
    }
}

// ---------------------------------------------------------------------------
// MFMA flash attention, double-buffered. grid = (B*H, 32), 4 waves.
// qt = 31 - blockIdx.y (heavy blocks dispatched first).
// Per iter: stage(t+1 -> buf^1), compute(t on buf), vmcnt(0)+s_barrier.
// LDS: buf0 K/V [0,16K), buf1 K/V [16K,32K), P tiles [32K,40K).
// ---------------------------------------------------------------------------
__global__ __launch_bounds__(256) void attn_mfma(
    const unsigned short* __restrict__ q, const unsigned short* __restrict__ k,
    const unsigned short* __restrict__ vt, unsigned short* __restrict__ ctx)
{
    const int bh = blockIdx.x;          // b*H + h
    const int qt = 31 - blockIdx.y;
    const int tid = threadIdx.x;
    const int lane = tid & 63, wq = tid >> 6;
    const int lx = lane & 15, hi = lane >> 4;

    __shared__ __align__(16) char smem[40960];
    char* Pw = &smem[32768 + wq * 2048];

    const int b = bh >> 4, h = bh & (H_ - 1);

    // Q fragments: lane holds Q[wq*16+lx][hi*8 + 32ks + 0..7]
    short8 qf[2];
    {
        const unsigned short* qrow =
            q + ((size_t)bh * S_ + qt * 64 + wq * 16 + lx) * 64;
        qf[0] = *(const short8*)&qrow[hi * 8];
        qf[1] = *(const short8*)&qrow[32 + hi * 8];
    }

    f32x4 o[4] = {};                    // O[hi*4+r][ct*16+lx]
    float m = -INFINITY, l = 0.f;       // state for q-row (wq*16+lx)
    const int qg = qt * 64 + wq * 16 + lx;

    // ---- prologue: stage tile 0 into buf0 ----
    {
        #pragma unroll
        for (int c = 0; c < 2; ++c) {
            int u = c * 256 + tid;
            int r = u >> 3, sp = u & 7, sl = sp ^ (r & 7);
            gload_lds16(&k[((size_t)bh * S_ + r) * 64 + sl * 8], &smem[u * 16]);
        }
        #pragma unroll
        for (int c = 0; c < 2; ++c) {
            int u = c * 256 + tid;
            int r = u >> 3, sp = u & 7, sl = sp ^ (r & 7);
            gload_lds16(&vt[((size_t)bh * 64 + r) * S_ + sl * 8],
                        &smem[8192 + u * 16]);
        }
    }
    SYNC_VM0();

    int cur = 0;
    for (int kt = 0; kt <= qt; ++kt) {
        char* bufc = smem + cur * 16384;

        // ---- stage t+1 into the other buffer (latency hides under compute) ----
        if (kt < qt) {
            char* bufn = smem + (cur ^ 1) * 16384;
            #pragma unroll
            for (int c = 0; c < 2; ++c) {
                int u = c * 256 + tid;
                int r = u >> 3, sp = u & 7, sl = sp ^ (r & 7);
                gload_lds16(&k[((size_t)bh * S_ + (kt + 1) * 64 + r) * 64 + sl * 8],
                            &bufn[u * 16]);
            }
            #pragma unroll
            for (int c = 0; c < 2; ++c) {
                int u = c * 256 + tid;
                int r = u >> 3, sp = u & 7, sl = sp ^ (r & 7);
                gload_lds16(&vt[((size_t)bh * 64 + r) * S_ + (kt + 1) * 64 + sl * 8],
                            &bufn[8192 + u * 16]);
            }
        }

        // ---- QK^T (swapped): lane holds S[q=lx][kv=rt*16+hi*4+r] ----
        f32x4 s[4] = {};
        #pragma unroll
        for (int rt = 0; rt < 4; ++rt) {
            #pragma unroll
            for (int ks = 0; ks < 2; ++ks) {
                int row = rt * 16 + lx;
                int sp = (ks * 4 + hi) ^ (row & 7);
                short8 kf = *(const short8*)&bufc[row * 128 + sp * 16];
                s[rt] = __builtin_amdgcn_mfma_f32_16x16x32_bf16(
                    kf, qf[ks], s[rt], 0, 0, 0);
            }
        }

        // ---- causal mask (scale folded into Q) ----
        if (kt == qt) {
            #pragma unroll
            for (int rt = 0; rt < 4; ++rt)
                #pragma unroll
                for (int r = 0; r < 4; ++r) {
                    int kvg = kt * 64 + rt * 16 + hi * 4 + r;
                    if (kvg > qg) s[rt][r] = -INFINITY;
                }
        }

        // ---- online softmax in exp2 domain, row = lx ----
        float tmax = s[0][0];
        #pragma unroll
        for (int rt = 0; rt < 4; ++rt)
            tmax = fmaxf(tmax, fmaxf(fmaxf(s[rt][0], s[rt][1]),
                                     fmaxf(s[rt][2], s[rt][3])));
        tmax = fmaxf(tmax, __shfl_xor(tmax, 16));
        tmax = fmaxf(tmax, __shfl_xor(tmax, 32));

        if (__any(tmax > m + DEFER_THR)) {
            float mn = fmaxf(m, tmax);
            float corr = fast_exp2(m - mn);
            m = mn;
            float ps = 0.f;
            #pragma unroll
            for (int rt = 0; rt < 4; ++rt)
                #pragma unroll
                for (int r = 0; r < 4; ++r) {
                    s[rt][r] = fast_exp2(s[rt][r] - mn);
                    ps += s[rt][r];
                }
            ps += __shfl_xor(ps, 16);
            ps += __shfl_xor(ps, 32);
            l = l * corr + ps;
            #pragma unroll
            for (int r = 0; r < 4; ++r) {
                float cr = __shfl(corr, hi * 4 + r);
                #pragma unroll
                for (int ct = 0; ct < 4; ++ct) o[ct][r] *= cr;
            }
        } else {                        // deferred: m unchanged, corr = 1
            float ps = 0.f;
            #pragma unroll
            for (int rt = 0; rt < 4; ++rt)
                #pragma unroll
                for (int r = 0; r < 4; ++r) {
                    s[rt][r] = fast_exp2(s[rt][r] - m);
                    ps += s[rt][r];
                }
            ps += __shfl_xor(ps, 16);
            ps += __shfl_xor(ps, 32);
            l += ps;
        }

        // ---- P -> bf16 (cvt_pk) -> per-wave swizzled LDS tile [16 q][64 kv] ----
        #pragma unroll
        for (int rt = 0; rt < 4; ++rt) {
            uint2 pk;
            pk.x = cvt_pk_bf16(s[rt][0], s[rt][1]);
            pk.y = cvt_pk_bf16(s[rt][2], s[rt][3]);
            int sl = 2 * rt + (hi >> 1);
            *(uint2*)&Pw[lx * 128 + ((sl ^ (lx & 7)) * 16) + (hi & 1) * 8] = pk;
        }
        short8 pf[2];
        #pragma unroll
        for (int ks = 0; ks < 2; ++ks) {
            int sl = ks * 4 + hi;
            pf[ks] = *(const short8*)&Pw[lx * 128 + ((sl ^ (lx & 7)) * 16)];
        }

        // ---- PV: O[q][d] += P . V^T ----
        #pragma unroll
        for (int ct = 0; ct < 4; ++ct) {
            #pragma unroll
            for (int ks = 0; ks < 2; ++ks) {
                int row = ct * 16 + lx;
                int sp = (ks * 4 + hi) ^ (row & 7);
                short8 vf = *(const short8*)&bufc[8192 + row * 128 + sp * 16];
                o[ct] = __builtin_amdgcn_mfma_f32_16x16x32_bf16(
                    pf[ks], vf, o[ct], 0, 0, 0);
            }
        }

        SYNC_VM0();                     // t+1 loads landed; all waves done w/ bufc
        cur ^= 1;
    }

    // ---- epilogue: ctx bf16 [B,S,D] ----
    #pragma unroll
    for (int r = 0; r < 4; ++r) {
        float inv = 1.0f / __shfl(l, hi * 4 + r);
        int srow = qt * 64 + wq * 16 + hi * 4 + r;
        #pragma unroll
        for (int ct = 0; ct < 4; ++ct)
            ctx[((size_t)(b * S_ + srow)) * D_ + h * 64 + ct * 16 + lx] =
                f2bf(o[ct][r] * inv);
    }
}

// ---------------------------------------------------------------------------
extern "C" void kernel_launch(void* const* d_in, const int* in_sizes, int n_in,
                              void* d_out, int out_size, void* d_ws, size_t ws_size,
                              hipStream_t stream)
{
    const float* x  = (const float*)d_in[0];
    const float* Wq = (const float*)d_in[1];
    const float* bq = (const float*)d_in[2];
    const float* Wk = (const float*)d_in[3];
    const float* bk = (const float*)d_in[4];
    const float* Wv = (const float*)d_in[5];
    const float* bv = (const float*)d_in[6];
    const float* Wo = (const float*)d_in[7];
    const float* bo = (const float*)d_in[8];
    float* out = (float*)d_out;

    const size_t per = (size_t)B_ * H_ * S_ * DH_;       // 4,194,304
    unsigned short* qb  = (unsigned short*)d_ws;
    unsigned short* kb  = qb + per;
    unsigned short* vtb = kb + per;
    unsigned short* xb  = vtb + per;
    unsigned short* wt  = xb + per;                      // 4 x 1M bf16
    unsigned short* cb  = xb;                            // ctx aliases xb

    cvt_x_k<<<2048, 256, 0, stream>>>(x, xb);
    tr_w_k<<<dim3(16, 16, 4), 256, 0, stream>>>(Wq, Wk, Wv, Wo, wt);

    gemm_bf16<1><<<dim3(32, 8, 3), 256, 0, stream>>>(
        xb, wt, bq, bk, bv, qb, kb, vtb);

    attn_mfma<<<dim3(32, 32), 256, 0, stream>>>(qb, kb, vtb, cb);

    gemm_bf16<0><<<dim3(32, 8, 1), 256, 0, stream>>>(
        cb, wt + 3u * 1048576u, bo, nullptr, nullptr, out, nullptr, nullptr);
}